// Round 8
// baseline (100.366 us; speedup 1.0000x reference)
//
#include <hip/hip_runtime.h>
#include <math.h>

#define N_DIM 64
#define C_DIM 512
#define K_DIM 64
#define P_DIM 900
#define P_PAD 928          // 29 * 32 (agg K-steps of 32)
#define PTILES 15          // assign p-blocks of 64

typedef __attribute__((ext_vector_type(8))) short short8;   // 8 bf16 = 4 VGPR
typedef __attribute__((ext_vector_type(4))) float f32x4;    // MFMA C/D

#define A2_ELEMS   ((size_t)N_DIM * K_DIM * P_PAD)

// fp32 -> bf16 bits, round-to-nearest-even (inputs finite)
__device__ inline ushort f2bf(float f) {
  uint u = __builtin_bit_cast(uint, f);
  u += 0x7FFFu + ((u >> 16) & 1u);
  return (ushort)(u >> 16);
}

// ---------------------------------------------------------------------------
// Kernel A (v2): logits GEMM via MFMA + fused L2-norm + softmax, NO x LDS.
// Block = (p-tile of 64, n); 4 waves, wave w owns k in [16w,16w+16).
// B-fragments (x) loaded directly from global (fp32->bf16 in flight); the
// block's 131 KB x-slice is read by all 4 waves -> L1/L2 absorbs redundancy.
// ssq accumulated from the same loaded values; invn via shfl_xor(16,32).
// Writes a2[n,k,p] = softmax*invn (bf16, zero-padded to P_PAD),
//        asum_part[n,k,ptile] = sum_p softmax (fp32).
// ---------------------------------------------------------------------------
__global__ __launch_bounds__(256) void netvlad_assign(
    const float* __restrict__ x, const float* __restrict__ w,
    ushort* __restrict__ a2, float* __restrict__ asum_part)
{
  const int n = blockIdx.y, bpt = blockIdx.x, p0 = bpt * 64;
  const int tid = threadIdx.x, wave = tid >> 6, lane = tid & 63;
  const int l15 = lane & 15, lhi = lane >> 4;

  __shared__ float wredm[4][4][16];
  __shared__ float wreds[4][4][16];

  // ---- W fragment preload (fp32 -> bf16 regs), k-slot = ks*32 + lhi*8 + j
  short8 wfrag[16];
  const float* wrow = w + (size_t)(wave * 16 + l15) * C_DIM + lhi * 8;
#pragma unroll
  for (int ks = 0; ks < 16; ++ks) {
    float4 f0 = *(const float4*)(wrow + ks * 32);
    float4 f1 = *(const float4*)(wrow + ks * 32 + 4);
    short8 t;
    t[0] = (short)f2bf(f0.x); t[1] = (short)f2bf(f0.y);
    t[2] = (short)f2bf(f0.z); t[3] = (short)f2bf(f0.w);
    t[4] = (short)f2bf(f1.x); t[5] = (short)f2bf(f1.y);
    t[6] = (short)f2bf(f1.z); t[7] = (short)f2bf(f1.w);
    wfrag[ks] = t;
  }

  // ---- per-pt x column base (clamped pixel; invalid lanes discarded later)
  const float* xb = x + (size_t)n * C_DIM * P_DIM;
  const float* xcol[4];
#pragma unroll
  for (int pt = 0; pt < 4; ++pt) {
    int pp = p0 + pt * 16 + l15;
    xcol[pt] = xb + (pp < P_DIM ? pp : (P_DIM - 1));
  }

  // ---- MFMA main loop: direct-global B-fragments + fused ssq
  f32x4 acc[4];
#pragma unroll
  for (int pt = 0; pt < 4; ++pt) acc[pt] = (f32x4){0.f, 0.f, 0.f, 0.f};
  float ssqp[4] = {0.f, 0.f, 0.f, 0.f};

  for (int ks = 0; ks < 16; ++ks) {
    const size_t coff = (size_t)(ks * 32 + lhi * 8) * P_DIM;
#pragma unroll
    for (int pt = 0; pt < 4; ++pt) {
      const float* src = xcol[pt] + coff;
      float v0 = src[0 * P_DIM], v1 = src[1 * P_DIM];
      float v2 = src[2 * P_DIM], v3 = src[3 * P_DIM];
      float v4 = src[4 * P_DIM], v5 = src[5 * P_DIM];
      float v6 = src[6 * P_DIM], v7 = src[7 * P_DIM];
      ssqp[pt] += v0 * v0 + v1 * v1 + v2 * v2 + v3 * v3
                + v4 * v4 + v5 * v5 + v6 * v6 + v7 * v7;
      short8 xf;
      xf[0] = (short)f2bf(v0); xf[1] = (short)f2bf(v1);
      xf[2] = (short)f2bf(v2); xf[3] = (short)f2bf(v3);
      xf[4] = (short)f2bf(v4); xf[5] = (short)f2bf(v5);
      xf[6] = (short)f2bf(v6); xf[7] = (short)f2bf(v7);
      acc[pt] = __builtin_amdgcn_mfma_f32_16x16x32_bf16(wfrag[ks], xf, acc[pt], 0, 0, 0);
    }
  }

  // ---- invn per pixel: full ssq = sum over the 4 lhi octet-groups
  float linv[4];
#pragma unroll
  for (int pt = 0; pt < 4; ++pt) {
    float s = ssqp[pt];
    s += __shfl_xor(s, 16);
    s += __shfl_xor(s, 32);
    linv[pt] = 1.0f / fmaxf(sqrtf(s), 1e-12f);
  }

  // ---- softmax over k (64 values per pixel column, cross-wave via LDS)
  float lg[4][4];
#pragma unroll
  for (int pt = 0; pt < 4; ++pt) {
    float m = -1e30f;
#pragma unroll
    for (int r = 0; r < 4; ++r) { lg[pt][r] = acc[pt][r] * linv[pt]; m = fmaxf(m, lg[pt][r]); }
    m = fmaxf(m, __shfl_xor(m, 16));
    m = fmaxf(m, __shfl_xor(m, 32));
    if (lhi == 0) wredm[wave][pt][l15] = m;
  }
  __syncthreads();
#pragma unroll
  for (int pt = 0; pt < 4; ++pt) {
    float m = fmaxf(fmaxf(wredm[0][pt][l15], wredm[1][pt][l15]),
                    fmaxf(wredm[2][pt][l15], wredm[3][pt][l15]));
    float s = 0.f;
#pragma unroll
    for (int r = 0; r < 4; ++r) { lg[pt][r] = __expf(lg[pt][r] - m); s += lg[pt][r]; }
    s += __shfl_xor(s, 16);
    s += __shfl_xor(s, 32);
    if (lhi == 0) wreds[wave][pt][l15] = s;
  }
  __syncthreads();

  ushort* a2b = a2 + (size_t)n * K_DIM * P_PAD;
  float asr[4] = {0.f, 0.f, 0.f, 0.f};
#pragma unroll
  for (int pt = 0; pt < 4; ++pt) {
    float stot = wreds[0][pt][l15] + wreds[1][pt][l15] +
                 wreds[2][pt][l15] + wreds[3][pt][l15];
    float rs = 1.0f / stot;
    int p = p0 + pt * 16 + l15;
    bool vv = p < P_DIM;
#pragma unroll
    for (int r = 0; r < 4; ++r) {
      float a = lg[pt][r] * rs;
      if (vv) asr[r] += a;
      if (p < P_PAD) {
        int k = wave * 16 + lhi * 4 + r;
        a2b[(size_t)k * P_PAD + p] = vv ? f2bf(a * linv[pt]) : (ushort)0;
      }
    }
  }
  // asum over this block's pixels: reduce across l15 lanes
#pragma unroll
  for (int r = 0; r < 4; ++r) {
    float v = asr[r];
    v += __shfl_xor(v, 1); v += __shfl_xor(v, 2);
    v += __shfl_xor(v, 4); v += __shfl_xor(v, 8);
    if (l15 == 0) {
      int k = wave * 16 + lhi * 4 + r;
      asum_part[((size_t)n * K_DIM + k) * PTILES + bpt] = v;
    }
  }
}

// ---------------------------------------------------------------------------
// Kernel B: agg[n,k,c] = sum_p a2[k,p]*x[c,p] via MFMA (A=a2, B=x direct from
// global, fp32->bf16 in flight). Block = (c-tile of 64, n); wave w owns c-col
// subtile 16w. Fused epilogue: out = acc - asum*centroid. x read exactly once.
// ---------------------------------------------------------------------------
__global__ __launch_bounds__(256) void netvlad_agg(
    const float* __restrict__ x, const ushort* __restrict__ a2,
    const float* __restrict__ asum_part, const float* __restrict__ cent,
    float* __restrict__ out)
{
  const int n = blockIdx.y, ct = blockIdx.x, c0 = ct * 64;
  const int tid = threadIdx.x, wave = tid >> 6, lane = tid & 63;
  const int l15 = lane & 15, lhi = lane >> 4;

  __shared__ float asum_s[64];
  if (tid < 64) {
    const float* ap = asum_part + ((size_t)n * K_DIM + tid) * PTILES;
    float s = 0.f;
#pragma unroll
    for (int j = 0; j < PTILES; ++j) s += ap[j];
    asum_s[tid] = s;
  }
  __syncthreads();

  f32x4 acc[4];
#pragma unroll
  for (int mt = 0; mt < 4; ++mt) acc[mt] = (f32x4){0.f, 0.f, 0.f, 0.f};

  const float*  xrow = x + (size_t)n * C_DIM * P_DIM
                         + (size_t)(c0 + wave * 16 + l15) * P_DIM;
  const ushort* ab   = a2 + (size_t)n * K_DIM * P_PAD;

  for (int ks = 0; ks < 29; ++ks) {
    int pb = ks * 32 + lhi * 8;
    short8 bfrag;
    if (pb + 8 <= P_DIM) {
      float4 f0 = *(const float4*)(xrow + pb);
      float4 f1 = *(const float4*)(xrow + pb + 4);
      bfrag[0] = (short)f2bf(f0.x); bfrag[1] = (short)f2bf(f0.y);
      bfrag[2] = (short)f2bf(f0.z); bfrag[3] = (short)f2bf(f0.w);
      bfrag[4] = (short)f2bf(f1.x); bfrag[5] = (short)f2bf(f1.y);
      bfrag[6] = (short)f2bf(f1.z); bfrag[7] = (short)f2bf(f1.w);
    } else {
#pragma unroll
      for (int j = 0; j < 8; ++j)
        bfrag[j] = (pb + j < P_DIM) ? (short)f2bf(xrow[pb + j]) : (short)0;
    }
#pragma unroll
    for (int mt = 0; mt < 4; ++mt) {
      short8 afrag = *(const short8*)(ab + (size_t)(mt * 16 + l15) * P_PAD
                                         + ks * 32 + lhi * 8);
      acc[mt] = __builtin_amdgcn_mfma_f32_16x16x32_bf16(afrag, bfrag, acc[mt], 0, 0, 0);
    }
  }

  const int c = c0 + wave * 16 + l15;
#pragma unroll
  for (int mt = 0; mt < 4; ++mt) {
#pragma unroll
    for (int r = 0; r < 4; ++r) {
      int k = mt * 16 + lhi * 4 + r;
      out[((size_t)n * K_DIM + k) * C_DIM + c] =
          acc[mt][r] - asum_s[k] * cent[(size_t)k * C_DIM + c];
    }
  }
}

extern "C" void kernel_launch(void* const* d_in, const int* in_sizes, int n_in,
                              void* d_out, int out_size, void* d_ws, size_t ws_size,
                              hipStream_t stream) {
  const float* x    = (const float*)d_in[0];
  const float* w    = (const float*)d_in[1];
  const float* cent = (const float*)d_in[2];
  float* out = (float*)d_out;

  ushort* a2        = (ushort*)d_ws;
  float*  asum_part = (float*)((char*)d_ws + A2_ELEMS * sizeof(ushort));

  netvlad_assign<<<dim3(PTILES, N_DIM), 256, 0, stream>>>(x, w, a2, asum_part);
  netvlad_agg   <<<dim3(8, N_DIM),      256, 0, stream>>>(x, a2, asum_part, cent, out);
}

// Round 9
// 98.059 us; speedup vs baseline: 1.0235x; 1.0235x over previous
//
#include <hip/hip_runtime.h>
#include <math.h>

#define N_DIM 64
#define C_DIM 512
#define K_DIM 64
#define P_DIM 900
#define P_PAD 928          // 29 * 32 (agg K-steps of 32)
#define PTILES 15          // assign p-blocks of 64

typedef __attribute__((ext_vector_type(8))) short short8;   // 8 bf16 = 4 VGPR
typedef __attribute__((ext_vector_type(4))) float f32x4;    // MFMA C/D

#define A2_ELEMS   ((size_t)N_DIM * K_DIM * P_PAD)

// fp32 -> bf16 bits, round-to-nearest-even (inputs finite)
__device__ inline ushort f2bf(float f) {
  uint u = __builtin_bit_cast(uint, f);
  u += 0x7FFFu + ((u >> 16) & 1u);
  return (ushort)(u >> 16);
}

// ---------------------------------------------------------------------------
// Kernel A (v3): logits GEMM via MFMA + fused L2-norm + softmax, NO x LDS.
// Block = (p-tile of 64, n); 4 waves, wave w owns k in [16w,16w+16).
// B-fragments (x) loaded directly from global (fp32->bf16 in flight).
// __launch_bounds__(256, 2): 2 waves/EU -> 256-VGPR budget so wfrag[16]
// (64 VGPRs) stays register-resident (round-8 regression: 56-VGPR target
// spilled it to scratch -> 70 MB scratch writes).
// ---------------------------------------------------------------------------
__global__ __launch_bounds__(256, 2) void netvlad_assign(
    const float* __restrict__ x, const float* __restrict__ w,
    ushort* __restrict__ a2, float* __restrict__ asum_part)
{
  const int n = blockIdx.y, bpt = blockIdx.x, p0 = bpt * 64;
  const int tid = threadIdx.x, wave = tid >> 6, lane = tid & 63;
  const int l15 = lane & 15, lhi = lane >> 4;

  __shared__ float wredm[4][4][16];
  __shared__ float wreds[4][4][16];

  // ---- W fragment preload (fp32 -> bf16 regs), k-slot = ks*32 + lhi*8 + j
  short8 wfrag[16];
  const float* wrow = w + (size_t)(wave * 16 + l15) * C_DIM + lhi * 8;
#pragma unroll
  for (int ks = 0; ks < 16; ++ks) {
    float4 f0 = *(const float4*)(wrow + ks * 32);
    float4 f1 = *(const float4*)(wrow + ks * 32 + 4);
    short8 t;
    t[0] = (short)f2bf(f0.x); t[1] = (short)f2bf(f0.y);
    t[2] = (short)f2bf(f0.z); t[3] = (short)f2bf(f0.w);
    t[4] = (short)f2bf(f1.x); t[5] = (short)f2bf(f1.y);
    t[6] = (short)f2bf(f1.z); t[7] = (short)f2bf(f1.w);
    wfrag[ks] = t;
  }

  // ---- per-pt x column base (clamped pixel; invalid lanes discarded later)
  const float* xb = x + (size_t)n * C_DIM * P_DIM;
  const float* xcol[4];
#pragma unroll
  for (int pt = 0; pt < 4; ++pt) {
    int pp = p0 + pt * 16 + l15;
    xcol[pt] = xb + (pp < P_DIM ? pp : (P_DIM - 1));
  }

  // ---- MFMA main loop: direct-global B-fragments + fused ssq
  f32x4 acc[4];
#pragma unroll
  for (int pt = 0; pt < 4; ++pt) acc[pt] = (f32x4){0.f, 0.f, 0.f, 0.f};
  float ssqp[4] = {0.f, 0.f, 0.f, 0.f};

  for (int ks = 0; ks < 16; ++ks) {
    const size_t coff = (size_t)(ks * 32 + lhi * 8) * P_DIM;
#pragma unroll
    for (int pt = 0; pt < 4; ++pt) {
      const float* src = xcol[pt] + coff;
      float v0 = src[0 * P_DIM], v1 = src[1 * P_DIM];
      float v2 = src[2 * P_DIM], v3 = src[3 * P_DIM];
      float v4 = src[4 * P_DIM], v5 = src[5 * P_DIM];
      float v6 = src[6 * P_DIM], v7 = src[7 * P_DIM];
      ssqp[pt] += v0 * v0 + v1 * v1 + v2 * v2 + v3 * v3
                + v4 * v4 + v5 * v5 + v6 * v6 + v7 * v7;
      short8 xf;
      xf[0] = (short)f2bf(v0); xf[1] = (short)f2bf(v1);
      xf[2] = (short)f2bf(v2); xf[3] = (short)f2bf(v3);
      xf[4] = (short)f2bf(v4); xf[5] = (short)f2bf(v5);
      xf[6] = (short)f2bf(v6); xf[7] = (short)f2bf(v7);
      acc[pt] = __builtin_amdgcn_mfma_f32_16x16x32_bf16(wfrag[ks], xf, acc[pt], 0, 0, 0);
    }
  }

  // ---- invn per pixel: full ssq = sum over the 4 lhi octet-groups
  float linv[4];
#pragma unroll
  for (int pt = 0; pt < 4; ++pt) {
    float s = ssqp[pt];
    s += __shfl_xor(s, 16);
    s += __shfl_xor(s, 32);
    linv[pt] = 1.0f / fmaxf(sqrtf(s), 1e-12f);
  }

  // ---- softmax over k (64 values per pixel column, cross-wave via LDS)
  float lg[4][4];
#pragma unroll
  for (int pt = 0; pt < 4; ++pt) {
    float m = -1e30f;
#pragma unroll
    for (int r = 0; r < 4; ++r) { lg[pt][r] = acc[pt][r] * linv[pt]; m = fmaxf(m, lg[pt][r]); }
    m = fmaxf(m, __shfl_xor(m, 16));
    m = fmaxf(m, __shfl_xor(m, 32));
    if (lhi == 0) wredm[wave][pt][l15] = m;
  }
  __syncthreads();
#pragma unroll
  for (int pt = 0; pt < 4; ++pt) {
    float m = fmaxf(fmaxf(wredm[0][pt][l15], wredm[1][pt][l15]),
                    fmaxf(wredm[2][pt][l15], wredm[3][pt][l15]));
    float s = 0.f;
#pragma unroll
    for (int r = 0; r < 4; ++r) { lg[pt][r] = __expf(lg[pt][r] - m); s += lg[pt][r]; }
    s += __shfl_xor(s, 16);
    s += __shfl_xor(s, 32);
    if (lhi == 0) wreds[wave][pt][l15] = s;
  }
  __syncthreads();

  ushort* a2b = a2 + (size_t)n * K_DIM * P_PAD;
  float asr[4] = {0.f, 0.f, 0.f, 0.f};
#pragma unroll
  for (int pt = 0; pt < 4; ++pt) {
    float stot = wreds[0][pt][l15] + wreds[1][pt][l15] +
                 wreds[2][pt][l15] + wreds[3][pt][l15];
    float rs = 1.0f / stot;
    int p = p0 + pt * 16 + l15;
    bool vv = p < P_DIM;
#pragma unroll
    for (int r = 0; r < 4; ++r) {
      float a = lg[pt][r] * rs;
      if (vv) asr[r] += a;
      if (p < P_PAD) {
        int k = wave * 16 + lhi * 4 + r;
        a2b[(size_t)k * P_PAD + p] = vv ? f2bf(a * linv[pt]) : (ushort)0;
      }
    }
  }
  // asum over this block's pixels: reduce across l15 lanes
#pragma unroll
  for (int r = 0; r < 4; ++r) {
    float v = asr[r];
    v += __shfl_xor(v, 1); v += __shfl_xor(v, 2);
    v += __shfl_xor(v, 4); v += __shfl_xor(v, 8);
    if (l15 == 0) {
      int k = wave * 16 + lhi * 4 + r;
      asum_part[((size_t)n * K_DIM + k) * PTILES + bpt] = v;
    }
  }
}

// ---------------------------------------------------------------------------
// Kernel B: agg[n,k,c] = sum_p a2[k,p]*x[c,p] via MFMA (A=a2, B=x direct from
// global, fp32->bf16 in flight). Block = (c-tile of 64, n); wave w owns c-col
// subtile 16w. Fused epilogue: out = acc - asum*centroid. x read exactly once.
// __launch_bounds__(256, 4): 128-VGPR budget, needs ~60 -> no spill risk.
// ---------------------------------------------------------------------------
__global__ __launch_bounds__(256, 4) void netvlad_agg(
    const float* __restrict__ x, const ushort* __restrict__ a2,
    const float* __restrict__ asum_part, const float* __restrict__ cent,
    float* __restrict__ out)
{
  const int n = blockIdx.y, ct = blockIdx.x, c0 = ct * 64;
  const int tid = threadIdx.x, wave = tid >> 6, lane = tid & 63;
  const int l15 = lane & 15, lhi = lane >> 4;

  __shared__ float asum_s[64];
  if (tid < 64) {
    const float* ap = asum_part + ((size_t)n * K_DIM + tid) * PTILES;
    float s = 0.f;
#pragma unroll
    for (int j = 0; j < PTILES; ++j) s += ap[j];
    asum_s[tid] = s;
  }
  __syncthreads();

  f32x4 acc[4];
#pragma unroll
  for (int mt = 0; mt < 4; ++mt) acc[mt] = (f32x4){0.f, 0.f, 0.f, 0.f};

  const float*  xrow = x + (size_t)n * C_DIM * P_DIM
                         + (size_t)(c0 + wave * 16 + l15) * P_DIM;
  const ushort* ab   = a2 + (size_t)n * K_DIM * P_PAD;

  for (int ks = 0; ks < 29; ++ks) {
    int pb = ks * 32 + lhi * 8;
    short8 bfrag;
    if (pb + 8 <= P_DIM) {
      float4 f0 = *(const float4*)(xrow + pb);
      float4 f1 = *(const float4*)(xrow + pb + 4);
      bfrag[0] = (short)f2bf(f0.x); bfrag[1] = (short)f2bf(f0.y);
      bfrag[2] = (short)f2bf(f0.z); bfrag[3] = (short)f2bf(f0.w);
      bfrag[4] = (short)f2bf(f1.x); bfrag[5] = (short)f2bf(f1.y);
      bfrag[6] = (short)f2bf(f1.z); bfrag[7] = (short)f2bf(f1.w);
    } else {
#pragma unroll
      for (int j = 0; j < 8; ++j)
        bfrag[j] = (pb + j < P_DIM) ? (short)f2bf(xrow[pb + j]) : (short)0;
    }
#pragma unroll
    for (int mt = 0; mt < 4; ++mt) {
      short8 afrag = *(const short8*)(ab + (size_t)(mt * 16 + l15) * P_PAD
                                         + ks * 32 + lhi * 8);
      acc[mt] = __builtin_amdgcn_mfma_f32_16x16x32_bf16(afrag, bfrag, acc[mt], 0, 0, 0);
    }
  }

  const int c = c0 + wave * 16 + l15;
#pragma unroll
  for (int mt = 0; mt < 4; ++mt) {
#pragma unroll
    for (int r = 0; r < 4; ++r) {
      int k = mt * 16 + lhi * 4 + r;
      out[((size_t)n * K_DIM + k) * C_DIM + c] =
          acc[mt][r] - asum_s[k] * cent[(size_t)k * C_DIM + c];
    }
  }
}

extern "C" void kernel_launch(void* const* d_in, const int* in_sizes, int n_in,
                              void* d_out, int out_size, void* d_ws, size_t ws_size,
                              hipStream_t stream) {
  const float* x    = (const float*)d_in[0];
  const float* w    = (const float*)d_in[1];
  const float* cent = (const float*)d_in[2];
  float* out = (float*)d_out;

  ushort* a2        = (ushort*)d_ws;
  float*  asum_part = (float*)((char*)d_ws + A2_ELEMS * sizeof(ushort));

  netvlad_assign<<<dim3(PTILES, N_DIM), 256, 0, stream>>>(x, w, a2, asum_part);
  netvlad_agg   <<<dim3(8, N_DIM),      256, 0, stream>>>(x, a2, asum_part, cent, out);
}

// Round 10
// 85.563 us; speedup vs baseline: 1.1730x; 1.1460x over previous
//
#include <hip/hip_runtime.h>
#include <math.h>

#define N_DIM 64
#define C_DIM 512
#define K_DIM 64
#define P_DIM 900
#define P_PAD 928          // 29 * 32 (agg K-steps of 32)
#define PTILES 15          // assign p-blocks of 64

typedef __attribute__((ext_vector_type(8))) short short8;   // 8 bf16 = 4 VGPR
typedef __attribute__((ext_vector_type(4))) float f32x4;    // MFMA C/D

#define A2_ELEMS   ((size_t)N_DIM * K_DIM * P_PAD)

// fp32 -> bf16 bits, round-to-nearest-even (inputs finite)
__device__ inline ushort f2bf(float f) {
  uint u = __builtin_bit_cast(uint, f);
  u += 0x7FFFu + ((u >> 16) & 1u);
  return (ushort)(u >> 16);
}

// ---------------------------------------------------------------------------
// Kernel A (v4): logits GEMM via MFMA + fused L2-norm + softmax, NO x LDS.
// Block = (p-tile of 64, n); 4 waves, wave w owns k in [16w,16w+16).
// B-fragments (x) loaded directly from global (fp32->bf16 in flight).
// CRITICAL: the ks main loop MUST be fully unrolled -- wfrag[ks] with a
// runtime index forces the whole 64-VGPR array into scratch (rule #20;
// rounds 8/9: VGPR_Count 52-56, 63 MB scratch writes, 110+ us).
// __launch_bounds__(256,2) grants the ~170-VGPR budget this needs.
// ---------------------------------------------------------------------------
__global__ __launch_bounds__(256, 2) void netvlad_assign(
    const float* __restrict__ x, const float* __restrict__ w,
    ushort* __restrict__ a2, float* __restrict__ asum_part)
{
  const int n = blockIdx.y, bpt = blockIdx.x, p0 = bpt * 64;
  const int tid = threadIdx.x, wave = tid >> 6, lane = tid & 63;
  const int l15 = lane & 15, lhi = lane >> 4;

  __shared__ float wredm[4][4][16];
  __shared__ float wreds[4][4][16];

  // ---- W fragment preload (fp32 -> bf16 regs), k-slot = ks*32 + lhi*8 + j
  short8 wfrag[16];
  const float* wrow = w + (size_t)(wave * 16 + l15) * C_DIM + lhi * 8;
#pragma unroll
  for (int ks = 0; ks < 16; ++ks) {
    float4 f0 = *(const float4*)(wrow + ks * 32);
    float4 f1 = *(const float4*)(wrow + ks * 32 + 4);
    short8 t;
    t[0] = (short)f2bf(f0.x); t[1] = (short)f2bf(f0.y);
    t[2] = (short)f2bf(f0.z); t[3] = (short)f2bf(f0.w);
    t[4] = (short)f2bf(f1.x); t[5] = (short)f2bf(f1.y);
    t[6] = (short)f2bf(f1.z); t[7] = (short)f2bf(f1.w);
    wfrag[ks] = t;
  }

  // ---- per-pt x column base (clamped pixel; invalid lanes discarded later)
  const float* xb = x + (size_t)n * C_DIM * P_DIM;
  const float* xcol[4];
#pragma unroll
  for (int pt = 0; pt < 4; ++pt) {
    int pp = p0 + pt * 16 + l15;
    xcol[pt] = xb + (pp < P_DIM ? pp : (P_DIM - 1));
  }

  // ---- MFMA main loop: direct-global B-fragments + fused ssq
  f32x4 acc[4];
#pragma unroll
  for (int pt = 0; pt < 4; ++pt) acc[pt] = (f32x4){0.f, 0.f, 0.f, 0.f};
  float ssqp[4] = {0.f, 0.f, 0.f, 0.f};

#pragma unroll
  for (int ks = 0; ks < 16; ++ks) {
    const size_t coff = (size_t)(ks * 32 + lhi * 8) * P_DIM;
#pragma unroll
    for (int pt = 0; pt < 4; ++pt) {
      const float* src = xcol[pt] + coff;
      float v0 = src[0 * P_DIM], v1 = src[1 * P_DIM];
      float v2 = src[2 * P_DIM], v3 = src[3 * P_DIM];
      float v4 = src[4 * P_DIM], v5 = src[5 * P_DIM];
      float v6 = src[6 * P_DIM], v7 = src[7 * P_DIM];
      ssqp[pt] += v0 * v0 + v1 * v1 + v2 * v2 + v3 * v3
                + v4 * v4 + v5 * v5 + v6 * v6 + v7 * v7;
      short8 xf;
      xf[0] = (short)f2bf(v0); xf[1] = (short)f2bf(v1);
      xf[2] = (short)f2bf(v2); xf[3] = (short)f2bf(v3);
      xf[4] = (short)f2bf(v4); xf[5] = (short)f2bf(v5);
      xf[6] = (short)f2bf(v6); xf[7] = (short)f2bf(v7);
      acc[pt] = __builtin_amdgcn_mfma_f32_16x16x32_bf16(wfrag[ks], xf, acc[pt], 0, 0, 0);
    }
  }

  // ---- invn per pixel: full ssq = sum over the 4 lhi octet-groups
  float linv[4];
#pragma unroll
  for (int pt = 0; pt < 4; ++pt) {
    float s = ssqp[pt];
    s += __shfl_xor(s, 16);
    s += __shfl_xor(s, 32);
    linv[pt] = 1.0f / fmaxf(sqrtf(s), 1e-12f);
  }

  // ---- softmax over k (64 values per pixel column, cross-wave via LDS)
  float lg[4][4];
#pragma unroll
  for (int pt = 0; pt < 4; ++pt) {
    float m = -1e30f;
#pragma unroll
    for (int r = 0; r < 4; ++r) { lg[pt][r] = acc[pt][r] * linv[pt]; m = fmaxf(m, lg[pt][r]); }
    m = fmaxf(m, __shfl_xor(m, 16));
    m = fmaxf(m, __shfl_xor(m, 32));
    if (lhi == 0) wredm[wave][pt][l15] = m;
  }
  __syncthreads();
#pragma unroll
  for (int pt = 0; pt < 4; ++pt) {
    float m = fmaxf(fmaxf(wredm[0][pt][l15], wredm[1][pt][l15]),
                    fmaxf(wredm[2][pt][l15], wredm[3][pt][l15]));
    float s = 0.f;
#pragma unroll
    for (int r = 0; r < 4; ++r) { lg[pt][r] = __expf(lg[pt][r] - m); s += lg[pt][r]; }
    s += __shfl_xor(s, 16);
    s += __shfl_xor(s, 32);
    if (lhi == 0) wreds[wave][pt][l15] = s;
  }
  __syncthreads();

  ushort* a2b = a2 + (size_t)n * K_DIM * P_PAD;
  float asr[4] = {0.f, 0.f, 0.f, 0.f};
#pragma unroll
  for (int pt = 0; pt < 4; ++pt) {
    float stot = wreds[0][pt][l15] + wreds[1][pt][l15] +
                 wreds[2][pt][l15] + wreds[3][pt][l15];
    float rs = 1.0f / stot;
    int p = p0 + pt * 16 + l15;
    bool vv = p < P_DIM;
#pragma unroll
    for (int r = 0; r < 4; ++r) {
      float a = lg[pt][r] * rs;
      if (vv) asr[r] += a;
      if (p < P_PAD) {
        int k = wave * 16 + lhi * 4 + r;
        a2b[(size_t)k * P_PAD + p] = vv ? f2bf(a * linv[pt]) : (ushort)0;
      }
    }
  }
  // asum over this block's pixels: reduce across l15 lanes
#pragma unroll
  for (int r = 0; r < 4; ++r) {
    float v = asr[r];
    v += __shfl_xor(v, 1); v += __shfl_xor(v, 2);
    v += __shfl_xor(v, 4); v += __shfl_xor(v, 8);
    if (l15 == 0) {
      int k = wave * 16 + lhi * 4 + r;
      asum_part[((size_t)n * K_DIM + k) * PTILES + bpt] = v;
    }
  }
}

// ---------------------------------------------------------------------------
// Kernel B: agg[n,k,c] = sum_p a2[k,p]*x[c,p] via MFMA (A=a2, B=x direct from
// global, fp32->bf16 in flight). Block = (c-tile of 64, n); wave w owns c-col
// subtile 16w. Fused epilogue: out = acc - asum*centroid. x read exactly once.
// No runtime-indexed register arrays (acc[mt] is statically unrolled).
// ---------------------------------------------------------------------------
__global__ __launch_bounds__(256, 4) void netvlad_agg(
    const float* __restrict__ x, const ushort* __restrict__ a2,
    const float* __restrict__ asum_part, const float* __restrict__ cent,
    float* __restrict__ out)
{
  const int n = blockIdx.y, ct = blockIdx.x, c0 = ct * 64;
  const int tid = threadIdx.x, wave = tid >> 6, lane = tid & 63;
  const int l15 = lane & 15, lhi = lane >> 4;

  __shared__ float asum_s[64];
  if (tid < 64) {
    const float* ap = asum_part + ((size_t)n * K_DIM + tid) * PTILES;
    float s = 0.f;
#pragma unroll
    for (int j = 0; j < PTILES; ++j) s += ap[j];
    asum_s[tid] = s;
  }
  __syncthreads();

  f32x4 acc[4];
#pragma unroll
  for (int mt = 0; mt < 4; ++mt) acc[mt] = (f32x4){0.f, 0.f, 0.f, 0.f};

  const float*  xrow = x + (size_t)n * C_DIM * P_DIM
                         + (size_t)(c0 + wave * 16 + l15) * P_DIM;
  const ushort* ab   = a2 + (size_t)n * K_DIM * P_PAD;

  for (int ks = 0; ks < 29; ++ks) {
    int pb = ks * 32 + lhi * 8;
    short8 bfrag;
    if (pb + 8 <= P_DIM) {
      float4 f0 = *(const float4*)(xrow + pb);
      float4 f1 = *(const float4*)(xrow + pb + 4);
      bfrag[0] = (short)f2bf(f0.x); bfrag[1] = (short)f2bf(f0.y);
      bfrag[2] = (short)f2bf(f0.z); bfrag[3] = (short)f2bf(f0.w);
      bfrag[4] = (short)f2bf(f1.x); bfrag[5] = (short)f2bf(f1.y);
      bfrag[6] = (short)f2bf(f1.z); bfrag[7] = (short)f2bf(f1.w);
    } else {
#pragma unroll
      for (int j = 0; j < 8; ++j)
        bfrag[j] = (pb + j < P_DIM) ? (short)f2bf(xrow[pb + j]) : (short)0;
    }
#pragma unroll
    for (int mt = 0; mt < 4; ++mt) {
      short8 afrag = *(const short8*)(ab + (size_t)(mt * 16 + l15) * P_PAD
                                         + ks * 32 + lhi * 8);
      acc[mt] = __builtin_amdgcn_mfma_f32_16x16x32_bf16(afrag, bfrag, acc[mt], 0, 0, 0);
    }
  }

  const int c = c0 + wave * 16 + l15;
#pragma unroll
  for (int mt = 0; mt < 4; ++mt) {
#pragma unroll
    for (int r = 0; r < 4; ++r) {
      int k = mt * 16 + lhi * 4 + r;
      out[((size_t)n * K_DIM + k) * C_DIM + c] =
          acc[mt][r] - asum_s[k] * cent[(size_t)k * C_DIM + c];
    }
  }
}

extern "C" void kernel_launch(void* const* d_in, const int* in_sizes, int n_in,
                              void* d_out, int out_size, void* d_ws, size_t ws_size,
                              hipStream_t stream) {
  const float* x    = (const float*)d_in[0];
  const float* w    = (const float*)d_in[1];
  const float* cent = (const float*)d_in[2];
  float* out = (float*)d_out;

  ushort* a2        = (ushort*)d_ws;
  float*  asum_part = (float*)((char*)d_ws + A2_ELEMS * sizeof(ushort));

  netvlad_assign<<<dim3(PTILES, N_DIM), 256, 0, stream>>>(x, w, a2, asum_part);
  netvlad_agg   <<<dim3(8, N_DIM),      256, 0, stream>>>(x, a2, asum_part, cent, out);
}

// Round 12
// 83.896 us; speedup vs baseline: 1.1963x; 1.0199x over previous
//
#include <hip/hip_runtime.h>
#include <math.h>

#define N_DIM 64
#define C_DIM 512
#define K_DIM 64
#define P_DIM 900
#define P_PAD 928          // 29 * 32 (agg K-steps of 32)
#define PTILES 15          // assign p-blocks of 64

typedef __attribute__((ext_vector_type(8))) short short8;   // 8 bf16 = 4 VGPR
typedef __attribute__((ext_vector_type(4))) float f32x4;    // MFMA C/D + x loads
typedef __attribute__((ext_vector_type(4))) uint  u32x4;

#define A2_ELEMS   ((size_t)N_DIM * K_DIM * P_PAD)

// fp32 -> bf16 bits, round-to-nearest-even (inputs finite)
__device__ inline ushort f2bf(float f) {
  uint u = __builtin_bit_cast(uint, f);
  u += 0x7FFFu + ((u >> 16) & 1u);
  return (ushort)(u >> 16);
}
// two fp32 -> one packed u32 of 2x bf16
__device__ inline uint pk2(float a, float b) {
  return (uint)f2bf(a) | ((uint)f2bf(b) << 16);
}

// ---------------------------------------------------------------------------
// Kernel A (v5): logits GEMM via MFMA + fused L2-norm + softmax, NO x LDS.
// Pixel mapping chosen for vector loads: pixel(pt,l15) = p0 + 4*l15 + pt.
// One float4 load along p per (c, lane) feeds component pt of all four
// pt-fragments: 8x16B loads per ks-step (vs 32 scalar) -- 128 VMEM insts
// per thread instead of 512.
// ks loop MUST stay fully unrolled (rule #20: wfrag[ks] runtime index
// -> 64-VGPR scratch spill, rounds 8/9).
// ---------------------------------------------------------------------------
__global__ __launch_bounds__(256, 2) void netvlad_assign(
    const float* __restrict__ x, const float* __restrict__ w,
    ushort* __restrict__ a2, float* __restrict__ asum_part)
{
  const int n = blockIdx.y, bpt = blockIdx.x, p0 = bpt * 64;
  const int tid = threadIdx.x, wave = tid >> 6, lane = tid & 63;
  const int l15 = lane & 15, lhi = lane >> 4;

  __shared__ float wredm[4][4][16];
  __shared__ float wreds[4][4][16];

  // ---- W fragment preload (fp32 -> bf16 regs), k-slot = ks*32 + lhi*8 + j
  short8 wfrag[16];
  const float* wrow = w + (size_t)(wave * 16 + l15) * C_DIM + lhi * 8;
#pragma unroll
  for (int ks = 0; ks < 16; ++ks) {
    f32x4 f0 = *(const f32x4*)(wrow + ks * 32);
    f32x4 f1 = *(const f32x4*)(wrow + ks * 32 + 4);
    u32x4 up;
    up[0] = pk2(f0[0], f0[1]); up[1] = pk2(f0[2], f0[3]);
    up[2] = pk2(f1[0], f1[1]); up[3] = pk2(f1[2], f1[3]);
    wfrag[ks] = __builtin_bit_cast(short8, up);
  }

  // ---- x load base: float4 along p at pb = p0 + 4*l15 (clamped, 16B-aligned)
  const float* xb = x + (size_t)n * C_DIM * P_DIM;
  int pb = p0 + 4 * l15;
  if (pb > P_DIM - 4) pb = P_DIM - 4;          // only last tile clamps
  const float* xbase = xb + pb + (size_t)(lhi * 8) * P_DIM;

  // ---- MFMA main loop: vector B-loads + fused ssq
  f32x4 acc[4];
#pragma unroll
  for (int pt = 0; pt < 4; ++pt) acc[pt] = (f32x4){0.f, 0.f, 0.f, 0.f};
  float ssqp[4] = {0.f, 0.f, 0.f, 0.f};

#pragma unroll
  for (int ks = 0; ks < 16; ++ks) {
    const float* src = xbase + (size_t)(ks * 32) * P_DIM;
    f32x4 xv0 = *(const f32x4*)(src + 0 * P_DIM);
    f32x4 xv1 = *(const f32x4*)(src + 1 * P_DIM);
    f32x4 xv2 = *(const f32x4*)(src + 2 * P_DIM);
    f32x4 xv3 = *(const f32x4*)(src + 3 * P_DIM);
    f32x4 xv4 = *(const f32x4*)(src + 4 * P_DIM);
    f32x4 xv5 = *(const f32x4*)(src + 5 * P_DIM);
    f32x4 xv6 = *(const f32x4*)(src + 6 * P_DIM);
    f32x4 xv7 = *(const f32x4*)(src + 7 * P_DIM);
#pragma unroll
    for (int pt = 0; pt < 4; ++pt) {
      ssqp[pt] += xv0[pt] * xv0[pt] + xv1[pt] * xv1[pt]
                + xv2[pt] * xv2[pt] + xv3[pt] * xv3[pt]
                + xv4[pt] * xv4[pt] + xv5[pt] * xv5[pt]
                + xv6[pt] * xv6[pt] + xv7[pt] * xv7[pt];
      u32x4 up;
      up[0] = pk2(xv0[pt], xv1[pt]); up[1] = pk2(xv2[pt], xv3[pt]);
      up[2] = pk2(xv4[pt], xv5[pt]); up[3] = pk2(xv6[pt], xv7[pt]);
      short8 xf = __builtin_bit_cast(short8, up);
      acc[pt] = __builtin_amdgcn_mfma_f32_16x16x32_bf16(wfrag[ks], xf, acc[pt], 0, 0, 0);
    }
  }

  // ---- invn per pixel: full ssq = sum over the 4 lhi octet-groups
  float linv[4];
#pragma unroll
  for (int pt = 0; pt < 4; ++pt) {
    float s = ssqp[pt];
    s += __shfl_xor(s, 16);
    s += __shfl_xor(s, 32);
    linv[pt] = 1.0f / fmaxf(sqrtf(s), 1e-12f);
  }

  // ---- softmax over k (64 values per pixel slot, cross-wave via LDS)
  float lg[4][4];
#pragma unroll
  for (int pt = 0; pt < 4; ++pt) {
    float m = -1e30f;
#pragma unroll
    for (int r = 0; r < 4; ++r) { lg[pt][r] = acc[pt][r] * linv[pt]; m = fmaxf(m, lg[pt][r]); }
    m = fmaxf(m, __shfl_xor(m, 16));
    m = fmaxf(m, __shfl_xor(m, 32));
    if (lhi == 0) wredm[wave][pt][l15] = m;
  }
  __syncthreads();
#pragma unroll
  for (int pt = 0; pt < 4; ++pt) {
    float m = fmaxf(fmaxf(wredm[0][pt][l15], wredm[1][pt][l15]),
                    fmaxf(wredm[2][pt][l15], wredm[3][pt][l15]));
    float s = 0.f;
#pragma unroll
    for (int r = 0; r < 4; ++r) { lg[pt][r] = __expf(lg[pt][r] - m); s += lg[pt][r]; }
    s += __shfl_xor(s, 16);
    s += __shfl_xor(s, 32);
    if (lhi == 0) wreds[wave][pt][l15] = s;
  }
  __syncthreads();

  ushort* a2b = a2 + (size_t)n * K_DIM * P_PAD;
  float asr[4] = {0.f, 0.f, 0.f, 0.f};
#pragma unroll
  for (int pt = 0; pt < 4; ++pt) {
    float stot = wreds[0][pt][l15] + wreds[1][pt][l15] +
                 wreds[2][pt][l15] + wreds[3][pt][l15];
    float rs = 1.0f / stot;
    int p = p0 + 4 * l15 + pt;          // vector-load pixel mapping
    bool vv = p < P_DIM;
#pragma unroll
    for (int r = 0; r < 4; ++r) {
      float a = lg[pt][r] * rs;
      if (vv) asr[r] += a;
      if (p < P_PAD) {
        int k = wave * 16 + lhi * 4 + r;
        a2b[(size_t)k * P_PAD + p] = vv ? f2bf(a * linv[pt]) : (ushort)0;
      }
    }
  }
  // asum over this block's pixels: reduce across l15 lanes
#pragma unroll
  for (int r = 0; r < 4; ++r) {
    float v = asr[r];
    v += __shfl_xor(v, 1); v += __shfl_xor(v, 2);
    v += __shfl_xor(v, 4); v += __shfl_xor(v, 8);
    if (l15 == 0) {
      int k = wave * 16 + lhi * 4 + r;
      asum_part[((size_t)n * K_DIM + k) * PTILES + bpt] = v;
    }
  }
}

// ---------------------------------------------------------------------------
// Kernel B: agg[n,k,c] = sum_p a2[k,p]*x[c,p] via MFMA (A=a2, B=x direct from
// global, fp32->bf16 in flight). Block = (c-tile of 64, n); wave w owns c-col
// subtile 16w. Fused epilogue: out = acc - asum*centroid. x read exactly once.
// ---------------------------------------------------------------------------
__global__ __launch_bounds__(256, 4) void netvlad_agg(
    const float* __restrict__ x, const ushort* __restrict__ a2,
    const float* __restrict__ asum_part, const float* __restrict__ cent,
    float* __restrict__ out)
{
  const int n = blockIdx.y, ct = blockIdx.x, c0 = ct * 64;
  const int tid = threadIdx.x, wave = tid >> 6, lane = tid & 63;
  const int l15 = lane & 15, lhi = lane >> 4;

  __shared__ float asum_s[64];
  if (tid < 64) {
    const float* ap = asum_part + ((size_t)n * K_DIM + tid) * PTILES;
    float s = 0.f;
#pragma unroll
    for (int j = 0; j < PTILES; ++j) s += ap[j];
    asum_s[tid] = s;
  }
  __syncthreads();

  f32x4 acc[4];
#pragma unroll
  for (int mt = 0; mt < 4; ++mt) acc[mt] = (f32x4){0.f, 0.f, 0.f, 0.f};

  const float*  xrow = x + (size_t)n * C_DIM * P_DIM
                         + (size_t)(c0 + wave * 16 + l15) * P_DIM;
  const ushort* ab   = a2 + (size_t)n * K_DIM * P_PAD;

  for (int ks = 0; ks < 29; ++ks) {
    int pb = ks * 32 + lhi * 8;
    short8 bfrag;
    if (pb + 8 <= P_DIM) {
      f32x4 f0 = *(const f32x4*)(xrow + pb);
      f32x4 f1 = *(const f32x4*)(xrow + pb + 4);
      u32x4 up;
      up[0] = pk2(f0[0], f0[1]); up[1] = pk2(f0[2], f0[3]);
      up[2] = pk2(f1[0], f1[1]); up[3] = pk2(f1[2], f1[3]);
      bfrag = __builtin_bit_cast(short8, up);
    } else {
#pragma unroll
      for (int j = 0; j < 8; ++j)
        bfrag[j] = (pb + j < P_DIM) ? (short)f2bf(xrow[pb + j]) : (short)0;
    }
#pragma unroll
    for (int mt = 0; mt < 4; ++mt) {
      short8 afrag = *(const short8*)(ab + (size_t)(mt * 16 + l15) * P_PAD
                                         + ks * 32 + lhi * 8);
      acc[mt] = __builtin_amdgcn_mfma_f32_16x16x32_bf16(afrag, bfrag, acc[mt], 0, 0, 0);
    }
  }

  const int c = c0 + wave * 16 + l15;
#pragma unroll
  for (int mt = 0; mt < 4; ++mt) {
#pragma unroll
    for (int r = 0; r < 4; ++r) {
      int k = mt * 16 + lhi * 4 + r;
      out[((size_t)n * K_DIM + k) * C_DIM + c] =
          acc[mt][r] - asum_s[k] * cent[(size_t)k * C_DIM + c];
    }
  }
}

extern "C" void kernel_launch(void* const* d_in, const int* in_sizes, int n_in,
                              void* d_out, int out_size, void* d_ws, size_t ws_size,
                              hipStream_t stream) {
  const float* x    = (const float*)d_in[0];
  const float* w    = (const float*)d_in[1];
  const float* cent = (const float*)d_in[2];
  float* out = (float*)d_out;

  ushort* a2        = (ushort*)d_ws;
  float*  asum_part = (float*)((char*)d_ws + A2_ELEMS * sizeof(ushort));

  netvlad_assign<<<dim3(PTILES, N_DIM), 256, 0, stream>>>(x, w, a2, asum_part);
  netvlad_agg   <<<dim3(8, N_DIM),      256, 0, stream>>>(x, a2, asum_part, cent, out);
}